// Round 4
// baseline (1240.109 us; speedup 1.0000x reference)
//
#include <hip/hip_runtime.h>
#include <stdint.h>
#include <math.h>

#define NN 6144
#define JJ 2000
#define HH 100
// Big-K layout: cols [0,100)=Q(or K) block, [100,128)=zero, [128,2128)=xn, [2128,2176)=zero
#define KB 2176
#define XOFF 128
#define KQK 2048   // K for QK-projection GEMM: xn cols (2000) + zero pad, read at A+XOFF

typedef __bf16 bf16;
typedef __bf16 bf16x8 __attribute__((ext_vector_type(8)));
typedef float f32x4 __attribute__((ext_vector_type(4)));

__device__ __forceinline__ void load_lds16(const void* g, void* l) {
  __builtin_amdgcn_global_load_lds(
      (const __attribute__((address_space(1))) void*)(uintptr_t)g,
      (__attribute__((address_space(3))) void*)(uint32_t)(uintptr_t)l,
      16, 0, 0);
}

// fast tanh: clamp to +-15 (tanh saturates in f32), then exp-based form.
__device__ __forceinline__ float ftanh(float x) {
  float xc = fminf(fmaxf(x, -15.f), 15.f);
  float e = __expf(2.f * xc);
  return (e - 1.f) / (e + 1.f);
}

// ---------------------------------------------------------------------------
// Legacy 128x128 kernel (kept for MODE 3: QK projection, N=256 only).
// ---------------------------------------------------------------------------
template <int MODE>
__global__ __launch_bounds__(256, 2) void gemm_bt(
    const bf16* __restrict__ A, const bf16* __restrict__ B,
    int lda, int ldb, int kdim,
    const float* __restrict__ p0, const float* __restrict__ p1,
    const float* __restrict__ p2,
    bf16* __restrict__ ob0, bf16* __restrict__ ob1,
    float* __restrict__ of0, float* __restrict__ rowsum)
{
  __shared__ alignas(16) bf16 As[128 * 64];
  __shared__ alignas(16) bf16 Bs[128 * 64];

  const int tid = threadIdx.x;
  const int lane = tid & 63;
  const int wv = tid >> 6;
  const int m0 = blockIdx.x * 128;
  const int n0 = blockIdx.y * 128;

  const int srow = lane >> 3;
  const int scol = ((lane & 7) ^ srow) * 8;
  const bf16* gA = A + (size_t)(m0 + wv * 32 + srow) * lda + scol;
  const bf16* gB = B + (size_t)(n0 + wv * 32 + srow) * ldb + scol;
  bf16* lA0 = &As[(wv * 32) * 64];
  bf16* lB0 = &Bs[(wv * 32) * 64];

  const int l15 = lane & 15;
  const int l4 = lane >> 4;
  const int s7 = l15 & 7;
  const int wm = (wv >> 1) * 64;
  const int wn = (wv & 1) * 64;
  const bf16* ra0 = &As[(wm + l15) * 64 + ((l4 ^ s7) * 8)];
  const bf16* ra1 = &As[(wm + l15) * 64 + (((l4 + 4) ^ s7) * 8)];
  const bf16* rb0 = &Bs[(wn + l15) * 64 + ((l4 ^ s7) * 8)];
  const bf16* rb1 = &Bs[(wn + l15) * 64 + (((l4 + 4) ^ s7) * 8)];

  f32x4 acc[4][4];
#pragma unroll
  for (int i = 0; i < 4; ++i)
#pragma unroll
    for (int j = 0; j < 4; ++j) acc[i][j] = {0.f, 0.f, 0.f, 0.f};

  const int kiters = kdim >> 6;
  for (int kt = 0; kt < kiters; ++kt) {
    __syncthreads();
#pragma unroll
    for (int it = 0; it < 4; ++it) {
      load_lds16(gA + (size_t)it * 8 * lda, lA0 + it * 512);
      load_lds16(gB + (size_t)it * 8 * ldb, lB0 + it * 512);
    }
    gA += 64;
    gB += 64;
    __syncthreads();
#pragma unroll
    for (int ks = 0; ks < 2; ++ks) {
      const bf16* ra = ks ? ra1 : ra0;
      const bf16* rb = ks ? rb1 : rb0;
      bf16x8 af[4], bb[4];
#pragma unroll
      for (int i = 0; i < 4; ++i)
        af[i] = *(const bf16x8*)(ra + i * 1024);
#pragma unroll
      for (int j = 0; j < 4; ++j)
        bb[j] = *(const bf16x8*)(rb + j * 1024);
#pragma unroll
      for (int i = 0; i < 4; ++i)
#pragma unroll
        for (int j = 0; j < 4; ++j)
          acc[i][j] = __builtin_amdgcn_mfma_f32_16x16x32_bf16(af[i], bb[j], acc[i][j], 0, 0, 0);
    }
  }

  const int row_base = m0 + wm + l4 * 4;
  const int col_base = n0 + wn + l15;

  if (MODE == 3) {
#pragma unroll
    for (int i = 0; i < 4; ++i) {
#pragma unroll
      for (int r = 0; r < 4; ++r) {
        int row = row_base + i * 16 + r;
        float nm = p0[row];
#pragma unroll
        for (int j = 0; j < 4; ++j) {
          int h = col_base + j * 16;
          float v = acc[i][j][r] * nm;
          if (h < HH) ob0[(size_t)row * KB + h] = (bf16)((v + p1[h]) * 0.1f);
          else if (h < 2 * HH) ob1[(size_t)row * KB + (h - HH)] = (bf16)(v + p2[h - HH]);
        }
      }
    }
  }
}

// ---------------------------------------------------------------------------
// 192x256 single-barrier double-buffered GEMM core.
// C[i,j] = sum_k A[i,k]*B[j,k]; 8 waves (2M x 4N), wave tile 96x64, BK=64.
// LDS: 2 x (A 192x64 + B 256x64) bf16 = 112 KiB, 16B-chunk XOR swizzle
// (phys_chunk = log_chunk ^ (row&7)); staging pre-swizzles the GLOBAL column.
//
// ONE barrier per K-tile. Measured model (rounds 1-3): per-K-tile time =
// sum over barrier-separated segments of max(LDS-port cy, MFMA cy) + 130/bar.
// Round-3 (2 segments): max(2216,931)+max(385,931)+260 = 3407 (meas 3410).
// Single segment: stage(T+1 -> buf^1) issued first (DMA, full-segment lead
// ~2600cy covers HBM-miss ~900cy), then 20 ds_reads + 48 MFMA freely
// scheduled, then __syncthreads() (compiler emits vmcnt(0)+lgkmcnt(0) drain
// before s_barrier — exactly the required WAR + DMA-visibility fences).
// Floor: max(LDS ~2500, MFMA 1862) + 130 ~= 2650 cy/K-tile.
// Race proof: T's stages target buf^1 whose last readers (tile T-1) drained
// (lgkmcnt0) before the previous barrier; T's ds_reads drain before T+1's
// stages issue; stage DMA completion forced by barrier's vmcnt(0).
// ---------------------------------------------------------------------------
__device__ __forceinline__ void gemm192_core(
    const bf16* __restrict__ A, const bf16* __restrict__ B,
    int lda, int ldb, int kdim, int m0, int n0, f32x4 (&acc)[6][4])
{
  __shared__ alignas(16) bf16 As[2][192 * 64];
  __shared__ alignas(16) bf16 Bs[2][256 * 64];

  const int tid = threadIdx.x;
  const int lane = tid & 63;
  const int wv = tid >> 6;        // 0..7
  const int wm = wv >> 2;         // 0..1 (M)
  const int wn = wv & 3;          // 0..3 (N)
  const int l15 = lane & 15;
  const int l4 = lane >> 4;
  const int s7 = lane & 7;
  const int srow = lane >> 3;
  const int scol = ((lane & 7) ^ srow) * 8;

  const bf16* gA = A + (size_t)(m0 + wv * 8 + srow) * lda + scol;
  const bf16* gB = B + (size_t)(n0 + wv * 8 + srow) * ldb + scol;

  const int c0 = (l4 ^ s7) * 8;         // ks=0 swizzled chunk offset (bf16 units)
  const int c1 = ((l4 + 4) ^ s7) * 8;   // ks=1

#pragma unroll
  for (int i = 0; i < 6; ++i)
#pragma unroll
    for (int j = 0; j < 4; ++j) acc[i][j] = {0.f, 0.f, 0.f, 0.f};

  const int kt = kdim >> 6;   // even for all call sites (96 / 34 / 32)

  // one call = 512 lanes x 16B = 64 rows x 64 cols (per wave: 8 rows from its base)
#define STA(bufi, h, T)                                                        \
  load_lds16(gA + (size_t)((h) * 64) * lda + (size_t)(T) * 64,                 \
             &As[(bufi)][((h) * 64 + wv * 8) * 64])
#define STB(bufi, h, T)                                                        \
  load_lds16(gB + (size_t)((h) * 64) * ldb + (size_t)(T) * 64,                 \
             &Bs[(bufi)][((h) * 64 + wv * 8) * 64])

  // prologue: stage tile 0 -> buf 0, drain, barrier
  STA(0, 0, 0); STA(0, 1, 0); STA(0, 2, 0);
  STB(0, 0, 0); STB(0, 1, 0); STB(0, 2, 0); STB(0, 3, 0);
  __syncthreads();

  for (int t2 = 0; t2 < kt; t2 += 2) {
#pragma unroll
    for (int u = 0; u < 2; ++u) {
      const int T = t2 + u;
      const int buf = u;
      // stage T+1 into the other buffer (issue first: DMA latency hides
      // under this tile's reads+MFMA; ~full segment of lead)
      if (T + 1 < kt) {
        STA(u ^ 1, 0, T + 1); STA(u ^ 1, 1, T + 1); STA(u ^ 1, 2, T + 1);
        STB(u ^ 1, 0, T + 1); STB(u ^ 1, 1, T + 1);
        STB(u ^ 1, 2, T + 1); STB(u ^ 1, 3, T + 1);
      }
      const bf16* pA = &As[buf][(wm * 96 + l15) * 64];
      const bf16* pB = &Bs[buf][(wn * 64 + l15) * 64];
      bf16x8 af[6][2], bb[4][2];
#pragma unroll
      for (int fm = 0; fm < 6; ++fm) {
        af[fm][0] = *(const bf16x8*)(pA + (fm * 16) * 64 + c0);
        af[fm][1] = *(const bf16x8*)(pA + (fm * 16) * 64 + c1);
      }
#pragma unroll
      for (int fn = 0; fn < 4; ++fn) {
        bb[fn][0] = *(const bf16x8*)(pB + (fn * 16) * 64 + c0);
        bb[fn][1] = *(const bf16x8*)(pB + (fn * 16) * 64 + c1);
      }
#pragma unroll
      for (int ks = 0; ks < 2; ++ks)
#pragma unroll
        for (int fm = 0; fm < 6; ++fm)
#pragma unroll
          for (int fn = 0; fn < 4; ++fn)
            acc[fm][fn] = __builtin_amdgcn_mfma_f32_16x16x32_bf16(
                af[fm][ks], bb[fn][ks], acc[fm][fn], 0, 0, 0);
      __syncthreads();   // vmcnt(0)+lgkmcnt(0) drain + barrier (one per K-tile)
    }
  }
#undef STA
#undef STB
}

// Merged logits + V-transpose launch, role interleaved in dispatch order:
// gid = dispatch-linear id; isl=(gid>>3)&1 so the role-pair sharing one
// B-panel (same work id) lands on the SAME XCD (gid and gid+8: same mod-8),
// roles mix 50/50 among co-resident blocks (tail packing + L2 reuse).
// Vt role skips the 128 all-zero head cols (kdim 2048, A/B offset XOFF).
__global__ __launch_bounds__(512, 2) void gemm256_lv(
    const bf16* __restrict__ Abig, const bf16* __restrict__ WvT,
    const bf16* __restrict__ Bbig,
    const float* __restrict__ sqv, const float* __restrict__ fv,
    const float* __restrict__ spos, const float* __restrict__ normv,
    const float* __restrict__ bv,
    bf16* __restrict__ P, bf16* __restrict__ Vt, float* __restrict__ rowsum)
{
  int gid = (blockIdx.z * 24 + blockIdx.y) * 32 + blockIdx.x;   // [0,1536)
  const bool isl = ((gid >> 3) & 1) == 0;
  int work = (gid & 7) | ((gid >> 4) << 3);                     // [0,768) bijective
  int swz = (work & 7) * 96 + (work >> 3);                      // XCD swizzle, 768%8==0
  const int m0 = (swz & 31) * 192;
  const int n0 = (swz >> 5) * 256;

  f32x4 acc[6][4];
  if (isl)
    gemm192_core(Abig, Bbig, KB, KB, KB, m0, n0, acc);
  else
    gemm192_core(WvT + XOFF, Bbig + XOFF, KB, KB, KQK, m0, n0, acc);

  const int tid = threadIdx.x;
  const int lane = tid & 63;
  const int wv = tid >> 6;
  const int wm = wv >> 2, wn = wv & 3;
  const int l15 = lane & 15, l4 = lane >> 4;
  const int row_base = m0 + wm * 96 + l4 * 4;
  const int col_base = n0 + wn * 64 + l15;

  if (isl) {
    // logits -> P = exp(QK/dk + cos + spatial + fdiff), rowsum atomics
    float sqc[4], fc[4], pxc[4], pyc[4];
#pragma unroll
    for (int j = 0; j < 4; ++j) {
      int c = col_base + j * 16;
      sqc[j] = sqv[c];
      fc[j] = fv[c];
      pxc[j] = spos[2 * c];
      pyc[j] = spos[2 * c + 1];
    }
#pragma unroll
    for (int i = 0; i < 6; ++i) {
#pragma unroll
      for (int r = 0; r < 4; ++r) {
        int row = row_base + i * 16 + r;
        float sqr = sqv[row], fr = fv[row];
        float pxr = spos[2 * row], pyr = spos[2 * row + 1];
        float rs = 0.f;
#pragma unroll
        for (int j = 0; j < 4; ++j) {
          int c = col_base + j * 16;
          float d2 = fmaxf(sqr + sqc[j] - 2.f * (pxr * pxc[j] + pyr * pyc[j]), 0.f);
          float lg = acc[i][j][r] + __expf(-0.5f * d2) + ftanh(fr - fc[j]);
          float e = __expf(lg);
          P[(size_t)row * NN + c] = (bf16)e;
          rs += e;
        }
        rs += __shfl_xor(rs, 1);
        rs += __shfl_xor(rs, 2);
        rs += __shfl_xor(rs, 4);
        rs += __shfl_xor(rs, 8);
        if (l15 == 0) atomicAdd(&rowsum[row], rs);
      }
    }
  } else {
    // Vt = acc*norm[col] + bv[row]
    float nc[4];
#pragma unroll
    for (int j = 0; j < 4; ++j) nc[j] = normv[col_base + j * 16];
#pragma unroll
    for (int i = 0; i < 6; ++i) {
#pragma unroll
      for (int r = 0; r < 4; ++r) {
        int row = row_base + i * 16 + r;
        float bvr = bv[row];
#pragma unroll
        for (int j = 0; j < 4; ++j)
          Vt[(size_t)row * NN + col_base + j * 16] = (bf16)(acc[i][j][r] * nc[j] + bvr);
      }
    }
  }
}

// out = (P @ V) / rowsum; grid 32x24 = 768 blocks = exactly 3.0 rounds.
// outp stores NON-TEMPORAL (never re-read; keep P+Vt in L3).
__global__ __launch_bounds__(512, 2) void gemm256_pv(
    const bf16* __restrict__ Pm, const bf16* __restrict__ Vt,
    const float* __restrict__ rowsum, float* __restrict__ outp)
{
  int lin = blockIdx.y * 32 + blockIdx.x;
  int swz = (lin & 7) * 96 + (lin >> 3);
  const int m0 = (swz & 31) * 192;
  const int n0 = (swz >> 5) * 256;

  f32x4 acc[6][4];
  gemm192_core(Pm, Vt, NN, NN, NN, m0, n0, acc);

  const int tid = threadIdx.x;
  const int lane = tid & 63;
  const int wv = tid >> 6;
  const int wm = wv >> 2, wn = wv & 3;
  const int l15 = lane & 15, l4 = lane >> 4;
  const int row_base = m0 + wm * 96 + l4 * 4;
  const int col_base = n0 + wn * 64 + l15;
#pragma unroll
  for (int i = 0; i < 6; ++i) {
#pragma unroll
    for (int r = 0; r < 4; ++r) {
      int row = row_base + i * 16 + r;
      float rinv = 1.f / rowsum[row];
#pragma unroll
      for (int j = 0; j < 4; ++j)
        __builtin_nontemporal_store(acc[i][j][r] * rinv,
                                    &outp[(size_t)row * NN + col_base + j * 16]);
    }
  }
}

// Per-row gene norm + write xn (bf16) into Abig & Bbig at XOFF, zero pads.
// Vectorized: float4 reads, bf16x8 writes.
__global__ void prep_xn(const float* __restrict__ gene, bf16* __restrict__ Ab,
                        bf16* __restrict__ Bb, float* __restrict__ normv)
{
  int row = blockIdx.x, tid = threadIdx.x;
  const f32x4* g4 = (const f32x4*)(gene + (size_t)row * JJ);   // 500 x float4
  float s = 0.f;
  for (int k = tid; k < 500; k += 256) {
    f32x4 v = g4[k];
    s += v[0] * v[0] + v[1] * v[1] + v[2] * v[2] + v[3] * v[3];
  }
#pragma unroll
  for (int m = 32; m >= 1; m >>= 1) s += __shfl_xor(s, m);
  __shared__ float red[4];
  if ((tid & 63) == 0) red[tid >> 6] = s;
  __syncthreads();
  float tot = red[0] + red[1] + red[2] + red[3];
  float nrm = sqrtf(tot);
  float rinv = 1.f / fmaxf(nrm, 1e-12f);
  if (tid == 0) normv[row] = nrm;
  bf16* a = Ab + (size_t)row * KB + XOFF;
  bf16* b = Bb + (size_t)row * KB + XOFF;
  for (int k = tid; k < 250; k += 256) {   // 250 chunks of 8
    f32x4 v0 = g4[2 * k], v1 = g4[2 * k + 1];
    bf16x8 o;
    o[0] = (bf16)(v0[0] * rinv); o[1] = (bf16)(v0[1] * rinv);
    o[2] = (bf16)(v0[2] * rinv); o[3] = (bf16)(v0[3] * rinv);
    o[4] = (bf16)(v1[0] * rinv); o[5] = (bf16)(v1[1] * rinv);
    o[6] = (bf16)(v1[2] * rinv); o[7] = (bf16)(v1[3] * rinv);
    *(bf16x8*)(a + k * 8) = o;
    *(bf16x8*)(b + k * 8) = o;
  }
  bf16* a0 = Ab + (size_t)row * KB;
  bf16* b0 = Bb + (size_t)row * KB;
  if (tid < 28) { a0[HH + tid] = (bf16)0.f; b0[HH + tid] = (bf16)0.f; }
  if (tid < 48) { a0[XOFF + JJ + tid] = (bf16)0.f; b0[XOFF + JJ + tid] = (bf16)0.f; }
}

// Per-row: sq = |p|^2 and f = (relu(tanh(sp@W1+b1)@W2+b2)@Wf + bf).
// 8 rows per block (128 threads): W-column read amortized 8x, 8 independent
// accumulators break the serial-FMA latency chain.
#define SFR 8
__global__ void prep_sf(const float* __restrict__ spos,
                        const float* __restrict__ Ws, const float* __restrict__ bs,
                        const float* __restrict__ W1, const float* __restrict__ b1,
                        const float* __restrict__ W2, const float* __restrict__ b2,
                        const float* __restrict__ Wf, const float* __restrict__ bfp,
                        float* __restrict__ sqv, float* __restrict__ fv)
{
  int row0 = blockIdx.x * SFR, tid = threadIdx.x;
  __shared__ float sp[SFR][HH], t1[SFR][HH], e2[SFR][HH];
  float px[SFR], py[SFR];
#pragma unroll
  for (int r = 0; r < SFR; ++r) {
    px[r] = spos[2 * (row0 + r)];
    py[r] = spos[2 * (row0 + r) + 1];
  }
  if (tid < SFR) sqv[row0 + tid] = px[tid] * px[tid] + py[tid] * py[tid];
  if (tid < HH) {
    float w0 = Ws[tid], w1 = Ws[HH + tid], bsv = bs[tid];
#pragma unroll
    for (int r = 0; r < SFR; ++r) sp[r][tid] = px[r] * w0 + py[r] * w1 + bsv;
  }
  __syncthreads();
  if (tid < HH) {
    float s[SFR];
#pragma unroll
    for (int r = 0; r < SFR; ++r) s[r] = b1[tid];
    for (int gi = 0; gi < HH; ++gi) {
      float w = W1[gi * HH + tid];
#pragma unroll
      for (int r = 0; r < SFR; ++r) s[r] += sp[r][gi] * w;
    }
#pragma unroll
    for (int r = 0; r < SFR; ++r) t1[r][tid] = ftanh(s[r]);
  }
  __syncthreads();
  if (tid < HH) {
    float s[SFR];
#pragma unroll
    for (int r = 0; r < SFR; ++r) s[r] = b2[tid];
    for (int gi = 0; gi < HH; ++gi) {
      float w = W2[gi * HH + tid];
#pragma unroll
      for (int r = 0; r < SFR; ++r) s[r] += t1[r][gi] * w;
    }
    float wf = Wf[tid];
#pragma unroll
    for (int r = 0; r < SFR; ++r) e2[r][tid] = fmaxf(s[r], 0.f) * wf;
  }
  __syncthreads();
  // 8 groups of 16 lanes; group g reduces row g
  int g = tid >> 4, l = tid & 15;
  float s = 0.f;
  for (int k = l; k < HH; k += 16) s += e2[g][k];
  s += __shfl_xor(s, 1);
  s += __shfl_xor(s, 2);
  s += __shfl_xor(s, 4);
  s += __shfl_xor(s, 8);
  if (l == 0) fv[row0 + g] = s + bfp[0];
}

// WqkT[h,k] = Wq[k,h] (h<100) / Wk[k,h-100] (100<=h<200), zero elsewhere. [256,2048] bf16.
__global__ void pack_wqk(const float* __restrict__ Wq, const float* __restrict__ Wk,
                         bf16* __restrict__ Wt)
{
  int idx = blockIdx.x * 256 + threadIdx.x;
  int h = idx >> 11;
  int k = idx & 2047;
  float v = 0.f;
  if (k < JJ) {
    if (h < HH) v = Wq[(size_t)k * HH + h];
    else if (h < 2 * HH) v = Wk[(size_t)k * HH + (h - HH)];
  }
  Wt[idx] = (bf16)v;
}

// WvT[o, XOFF+j] = Wv[j, o] (bf16), zero-padded j>=JJ. Tiled 32x32 transpose.
// (WvT cols [0,XOFF) are never read now -- Vt GEMM starts at XOFF.)
__global__ void pack_wvt(const float* __restrict__ Wv, bf16* __restrict__ Wt)
{
  __shared__ float tile[32][33];
  int tx = threadIdx.x & 31, ty = threadIdx.x >> 5;   // 32x8
  int o0 = blockIdx.x * 32, j0 = blockIdx.y * 32;
#pragma unroll
  for (int rr = 0; rr < 32; rr += 8) {
    int j = j0 + ty + rr;
    tile[ty + rr][tx] = (j < JJ) ? Wv[(size_t)j * NN + o0 + tx] : 0.f;
  }
  __syncthreads();
#pragma unroll
  for (int rr = 0; rr < 32; rr += 8) {
    int o = o0 + ty + rr;
    Wt[(size_t)o * KB + XOFF + j0 + tx] = (bf16)tile[tx][ty + rr];
  }
}

// attn[row, :] = P[row, :] / rowsum[row]; vectorized f32x4 NT stores.
__global__ void norm_attn(const bf16* __restrict__ P, const float* __restrict__ rowsum,
                          float* __restrict__ attn)
{
  int row = blockIdx.x;
  float rinv = 1.f / rowsum[row];
  const bf16x8* p = (const bf16x8*)(P + (size_t)row * NN);
  f32x4* dst = (f32x4*)(attn + (size_t)row * NN);
  for (int c = threadIdx.x; c < NN / 8; c += 256) {
    bf16x8 v = p[c];
    f32x4 o0 = {(float)v[0] * rinv, (float)v[1] * rinv,
                (float)v[2] * rinv, (float)v[3] * rinv};
    f32x4 o1 = {(float)v[4] * rinv, (float)v[5] * rinv,
                (float)v[6] * rinv, (float)v[7] * rinv};
    __builtin_nontemporal_store(o0, &dst[2 * c]);
    __builtin_nontemporal_store(o1, &dst[2 * c + 1]);
  }
}

extern "C" void kernel_launch(void* const* d_in, const int* in_sizes, int n_in,
                              void* d_out, int out_size, void* d_ws, size_t ws_size,
                              hipStream_t stream)
{
  const float* gene = (const float*)d_in[0];
  const float* spos = (const float*)d_in[1];
  const float* Wq = (const float*)d_in[2];
  const float* bq = (const float*)d_in[3];
  const float* Wk = (const float*)d_in[4];
  const float* bk = (const float*)d_in[5];
  const float* Wv = (const float*)d_in[6];
  const float* bv = (const float*)d_in[7];
  const float* Ws = (const float*)d_in[8];
  const float* bs = (const float*)d_in[9];
  const float* W1 = (const float*)d_in[10];
  const float* b1 = (const float*)d_in[11];
  const float* W2 = (const float*)d_in[12];
  const float* b2 = (const float*)d_in[13];
  const float* Wf = (const float*)d_in[14];
  const float* bfp = (const float*)d_in[15];

  char* ws = (char*)d_ws;
  bf16* Abig = (bf16*)ws;            ws += (size_t)NN * KB * 2;
  bf16* Bbig = (bf16*)ws;            ws += (size_t)NN * KB * 2;
  bf16* WvT  = (bf16*)ws;            ws += (size_t)NN * KB * 2;
  bf16* WqkT = (bf16*)ws;            ws += (size_t)256 * KQK * 2;
  bf16* P    = (bf16*)ws;            ws += (size_t)NN * NN * 2;
  float* rowsum = (float*)ws;        ws += (size_t)NN * 4;
  float* normv  = (float*)ws;        ws += (size_t)NN * 4;
  float* sqv    = (float*)ws;        ws += (size_t)NN * 4;
  float* fv     = (float*)ws;        ws += (size_t)NN * 4;

  float* attn = (float*)d_out;
  float* outp = (float*)d_out + (size_t)NN * NN;
  bf16* Vt = (bf16*)d_out;   // Vt (bf16, 75.5MB) lives in attn region until norm_attn

  hipMemsetAsync(rowsum, 0, NN * sizeof(float), stream);
  prep_xn<<<NN, 256, 0, stream>>>(gene, Abig, Bbig, normv);
  prep_sf<<<NN / SFR, 128, 0, stream>>>(spos, Ws, bs, W1, b1, W2, b2, Wf, bfp, sqv, fv);
  pack_wqk<<<(256 * KQK) / 256, 256, 0, stream>>>(Wq, Wk, WqkT);
  pack_wvt<<<dim3(NN / 32, KQK / 32), 256, 0, stream>>>(Wv, WvT);

  // QK projection: reads Abig cols [128,2176) only; writes cols [0,100) of Abig/Bbig
  gemm_bt<3><<<dim3(NN / 128, 2), 256, 0, stream>>>(
      Abig + XOFF, WqkT, KB, KQK, KQK, normv, bq, bk, Abig, Bbig, nullptr, nullptr);
  // merged logits + Vt, role-interleaved; 1536 blocks = exact 6.0 rounds
  gemm256_lv<<<dim3(32, 24, 2), 512, 0, stream>>>(
      Abig, WvT, Bbig, sqv, fv, spos, normv, bv, P, Vt, rowsum);
  // out = (P @ V) / rowsum; exact 3.0 rounds
  gemm256_pv<<<dim3(32, 24), 512, 0, stream>>>(P, Vt, rowsum, outp);
  // attn = P / rowsum (overwrites Vt region last)
  norm_attn<<<NN, 256, 0, stream>>>(P, rowsum, attn);
}